// Round 7
// baseline (139.657 us; speedup 1.0000x reference)
//
#include <hip/hip_runtime.h>

typedef _Float16 f16;
typedef _Float16 f16x2 __attribute__((ext_vector_type(2)));
typedef _Float16 f16x4 __attribute__((ext_vector_type(4)));
typedef _Float16 f16x8 __attribute__((ext_vector_type(8)));
typedef float f32x4 __attribute__((ext_vector_type(4)));

#define BB 4
#define CC 256
#define HH 128
#define WW 128
#define OWW 64
#define DD 4096     // 64*64
#define NPIX 16384  // 128*128

// Wq -> hi/lo f16 per-lane MFMA fragments:
// wq{h,l}[((kk*8+G)*256 + o)*8 + e] = split(Wq[o][kk*64 + G*8 + e])
__global__ void prep_wq_k(const float* __restrict__ Wq,
                          f16* __restrict__ wqh, f16* __restrict__ wql) {
    int t = blockIdx.x * 256 + threadIdx.x;   // 0..2047
    int G = t >> 8, o = t & 255;
#pragma unroll
    for (int kk = 0; kk < 4; ++kk) {
        const float* wr = Wq + (size_t)o * CC + kk * 64 + G * 8;
        float4 a = *(const float4*)wr;
        float4 b2 = *(const float4*)(wr + 4);
        float v[8] = {a.x, a.y, a.z, a.w, b2.x, b2.y, b2.z, b2.w};
        f16x8 hv, lv;
#pragma unroll
        for (int e = 0; e < 8; ++e) {
            f16 hh = (f16)v[e];
            hv[e] = hh;
            lv[e] = (f16)(v[e] - (float)hh);
        }
        size_t idx = (size_t)(((kk * 8 + G) * 256) + o) * 8;
        *(f16x8*)&wqh[idx] = hv;
        *(f16x8*)&wql[idx] = lv;
    }
}

// Fused qc = (Wq_h+Wq_l)@src + bq (f16 split MFMA, qc never stored) + dot epilogue.
// Block = (b, h-pair, w-half). 512 thr, 8 waves: rh = wv>>2, o0 = (wv&3)*64.
// dot partials: plain stores, dotp[slot=bid&127][k(9)][b*CC+o] — unique writer.
__global__ __launch_bounds__(512, 4) void qcdot_k(const float* __restrict__ src,
                                                  const float* __restrict__ feat,
                                                  const f16* __restrict__ wqh,
                                                  const f16* __restrict__ wql,
                                                  const float* __restrict__ bq,
                                                  float* __restrict__ dotp) {
    __shared__ __align__(16) f16 Bl[2][128 * 64];  // src [px][c-swz], dbuf 2x16KB
    __shared__ __align__(16) f16 Fl[512 * 36];     // feat [(o*2+yi)][36]  36.9KB

    int t = threadIdx.x;
    int bid = blockIdx.x;
    int b = bid >> 7;
    int hp = (bid >> 1) & 63;
    int wh = bid & 1;
    int h = hp * 2;
    int w0 = wh * 64;
    int x0 = wh * 32;
    int ybase = hp;

    // ---- prologue: issue kk=0 src loads ----
    const float* srcb = src + (size_t)b * CC * NPIX + h * WW + w0;
    int q4 = t & 15, rh_t = (t >> 4) & 1, c4 = t >> 5;
    const float* sp0 = srcb + (size_t)(c4 * 4) * NPIX + rh_t * WW + q4 * 4;
    float4 rr[4];
#pragma unroll
    for (int r = 0; r < 4; ++r) rr[r] = *(const float4*)(sp0 + (size_t)r * NPIX);

    // ---- stage feat tile (from f32): Fl[(o*2+yi)*36 + xi] ----
    {
        const float* fb = feat + (size_t)b * CC * DD;
        int o = t >> 1, yi = t & 1;
        int y = ybase + yi;
        const float* frow = fb + (size_t)o * DD + y * 64 + x0;
        f16* dst = &Fl[(o * 2 + yi) * 36];
        if (y < 64) {
#pragma unroll
            for (int k2 = 0; k2 < 8; ++k2) {
                float4 f = *(const float4*)&frow[k2 * 4];
                f16x4 hv = {(f16)f.x, (f16)f.y, (f16)f.z, (f16)f.w};
                *(f16x4*)&dst[k2 * 4] = hv;
            }
            dst[32] = (x0 + 32 < 64) ? (f16)frow[32] : (f16)0.f;
        } else {
            f16x4 z = {0, 0, 0, 0};
#pragma unroll
            for (int k2 = 0; k2 < 8; ++k2) *(f16x4*)&dst[k2 * 4] = z;
            dst[32] = (f16)0.f;
        }
    }

    int wv = t >> 6;
    int lane = t & 63;
    int g = lane >> 4;
    int col = lane & 15;
    int rh = wv >> 2;
    int o0 = (wv & 3) * 64;

    f32x4 acc[4][4];
#pragma unroll
    for (int mf = 0; mf < 4; ++mf)
#pragma unroll
        for (int nf = 0; nf < 4; ++nf) acc[mf][nf] = (f32x4){0.f, 0.f, 0.f, 0.f};

    int Gw = c4 >> 1, ho = (c4 & 1) << 2;

#pragma unroll
    for (int kk = 0; kk < 4; ++kk) {
        // (b) cvt + ds_write current src regs -> Bl[kk&1]
#pragma unroll
        for (int p = 0; p < 4; ++p) {
            int px = rh_t * 64 + q4 * 4 + p;
            f16x4 hv = {(f16)(&rr[0].x)[p], (f16)(&rr[1].x)[p],
                        (f16)(&rr[2].x)[p], (f16)(&rr[3].x)[p]};
            *(f16x4*)&Bl[kk & 1][px * 64 + ((Gw ^ (px & 7)) << 3) + ho] = hv;
        }
        // (c) issue next-kk src loads (in-place reuse) + s=0 Wq hi/lo frags
        if (kk < 3) {
            const float* spn = srcb + (size_t)((kk + 1) * 64 + c4 * 4) * NPIX + rh_t * WW + q4 * 4;
#pragma unroll
            for (int r = 0; r < 4; ++r) rr[r] = *(const float4*)(spn + (size_t)r * NPIX);
        }
        f16x8 bfh[4], bfl[4];
#pragma unroll
        for (int nf = 0; nf < 4; ++nf) {
            size_t idx = (size_t)(((kk * 8 + g) * 256) + o0 + nf * 16 + col) * 8;
            bfh[nf] = *(const f16x8*)&wqh[idx];
            bfl[nf] = *(const f16x8*)&wql[idx];
        }
        // (d) raw barrier: drain LDS ops only; global loads stay in flight
        __builtin_amdgcn_sched_barrier(0);
        asm volatile("s_waitcnt lgkmcnt(0)" ::: "memory");
        __builtin_amdgcn_sched_barrier(0);
        __builtin_amdgcn_s_barrier();
        __builtin_amdgcn_sched_barrier(0);
        // (e) MFMA s=0: hi + lo
#pragma unroll
        for (int mf = 0; mf < 4; ++mf) {
            int px = rh * 64 + mf * 16 + col;
            f16x8 af = *(const f16x8*)&Bl[kk & 1][px * 64 + ((g ^ (px & 7)) << 3)];
#pragma unroll
            for (int nf = 0; nf < 4; ++nf)
                acc[mf][nf] = __builtin_amdgcn_mfma_f32_16x16x32_f16(af, bfh[nf], acc[mf][nf], 0, 0, 0);
#pragma unroll
            for (int nf = 0; nf < 4; ++nf)
                acc[mf][nf] = __builtin_amdgcn_mfma_f32_16x16x32_f16(af, bfl[nf], acc[mf][nf], 0, 0, 0);
        }
        // s=1: reload frags, second half
#pragma unroll
        for (int nf = 0; nf < 4; ++nf) {
            size_t idx = (size_t)(((kk * 8 + 4 + g) * 256) + o0 + nf * 16 + col) * 8;
            bfh[nf] = *(const f16x8*)&wqh[idx];
            bfl[nf] = *(const f16x8*)&wql[idx];
        }
#pragma unroll
        for (int mf = 0; mf < 4; ++mf) {
            int px = rh * 64 + mf * 16 + col;
            int G2 = 4 + g;
            f16x8 af = *(const f16x8*)&Bl[kk & 1][px * 64 + ((G2 ^ (px & 7)) << 3)];
#pragma unroll
            for (int nf = 0; nf < 4; ++nf)
                acc[mf][nf] = __builtin_amdgcn_mfma_f32_16x16x32_f16(af, bfh[nf], acc[mf][nf], 0, 0, 0);
#pragma unroll
            for (int nf = 0; nf < 4; ++nf)
                acc[mf][nf] = __builtin_amdgcn_mfma_f32_16x16x32_f16(af, bfl[nf], acc[mf][nf], 0, 0, 0);
        }
    }

    // ---- epilogue ----
    int i0 = rh ? 2 : 1;
    float bqv[4];
#pragma unroll
    for (int nf = 0; nf < 4; ++nf) bqv[nf] = bq[o0 + nf * 16 + col];

    float bins[4][2][3];
#pragma unroll
    for (int nf = 0; nf < 4; ++nf)
#pragma unroll
        for (int ii = 0; ii < 2; ++ii)
#pragma unroll
            for (int j = 0; j < 3; ++j) bins[nf][ii][j] = 0.f;

#pragma unroll
    for (int mf = 0; mf < 4; ++mf) {
        int X = mf * 8 + g * 2;
#pragma unroll
        for (int ii = 0; ii < 2; ++ii) {
            if (ii == 1 && rh == 0) continue;   // wave-uniform skip
#pragma unroll
            for (int nf = 0; nf < 4; ++nf) {
                int o = o0 + nf * 16 + col;
                const f16* fr = &Fl[(o * 2 + ii) * 36];
                f16x2 lh = *(const f16x2*)&fr[X];
                float lo = (float)lh[0], hi = (float)lh[1];
                float s2 = (float)fr[X + 2];
                float qv0 = acc[mf][nf][0] + bqv[nf];
                float qv1 = acc[mf][nf][1] + bqv[nf];
                float qv2 = acc[mf][nf][2] + bqv[nf];
                float qv3 = acc[mf][nf][3] + bqv[nf];
                bins[nf][ii][1] += qv0 * lo + qv2 * hi;   // j=1 (even w)
                bins[nf][ii][2] += qv1 * lo + qv3 * hi;   // j=2 (odd w, left)
                bins[nf][ii][0] += qv1 * hi + qv3 * s2;   // j=0 (odd w, right)
            }
        }
    }

#pragma unroll
    for (int m = 16; m <= 32; m <<= 1)
#pragma unroll
        for (int nf = 0; nf < 4; ++nf)
#pragma unroll
            for (int ii = 0; ii < 2; ++ii) {
                if (ii == 1 && rh == 0) continue;
#pragma unroll
                for (int j = 0; j < 3; ++j)
                    bins[nf][ii][j] += __shfl_xor(bins[nf][ii][j], m, 64);
            }

    if (g == 0) {
        float* dslot = dotp + (size_t)(bid & 127) * (9 * BB * CC);
#pragma unroll
        for (int nf = 0; nf < 4; ++nf) {
            int bc = b * CC + o0 + nf * 16 + col;
            dslot[(i0 * 3 + 0) * (BB * CC) + bc] = bins[nf][0][0];
            dslot[(i0 * 3 + 1) * (BB * CC) + bc] = bins[nf][0][1];
            dslot[(i0 * 3 + 2) * (BB * CC) + bc] = bins[nf][0][2];
            if (rh) {
                dslot[0 * (BB * CC) + bc] = bins[nf][1][0];
                dslot[1 * (BB * CC) + bc] = bins[nf][1][1];
                dslot[2 * (BB * CC) + bc] = bins[nf][1][2];
            }
        }
    }
}

// v = (Wv_h+Wv_l)@(feat_h+feat_l) + bv, split f16 MFMA (3 products) -> vh f16.
// Block: 128 o x 128 d, waves 2x2.
__global__ __launch_bounds__(256, 2) void vc_k(const float* __restrict__ feat,
                                               const float* __restrict__ Wv,
                                               const float* __restrict__ bv,
                                               f16* __restrict__ vh) {
    __shared__ __align__(16) f16 Alh[128 * 64];
    __shared__ __align__(16) f16 All[128 * 64];
    __shared__ __align__(16) f16 Blh[128 * 64];
    __shared__ __align__(16) f16 Bll[128 * 64];
    int t = threadIdx.x;
    int bid = blockIdx.x;
    int b = bid >> 6;
    int rest = bid & 63;
    int o0 = (rest >> 5) * 128;
    int d0 = (rest & 31) * 128;

    int wv = t >> 6;
    int wm = wv >> 1, wn = wv & 1;
    int lane = t & 63;
    int g = lane >> 4;
    int col = lane & 15;

    f32x4 acc[4][4];
#pragma unroll
    for (int mf = 0; mf < 4; ++mf)
#pragma unroll
        for (int nf = 0; nf < 4; ++nf) acc[mf][nf] = (f32x4){0.f, 0.f, 0.f, 0.f};

    const float* featb = feat + (size_t)b * CC * DD + d0;

    for (int kk = 0; kk < 4; ++kk) {
        int c0 = kk * 64;
        {
            int orow = t >> 2;
            int cb = (t & 3) << 4;
#pragma unroll
            for (int oo = 0; oo < 2; ++oo) {
                int o = oo * 64 + orow;
                const float* wr = Wv + (size_t)(o0 + o) * CC + c0 + cb;
                float4 f0 = *(const float4*)(wr);
                float4 f1 = *(const float4*)(wr + 4);
                float4 f2 = *(const float4*)(wr + 8);
                float4 f3 = *(const float4*)(wr + 12);
                float v0[8] = {f0.x, f0.y, f0.z, f0.w, f1.x, f1.y, f1.z, f1.w};
                float v1[8] = {f2.x, f2.y, f2.z, f2.w, f3.x, f3.y, f3.z, f3.w};
                f16x8 h0, l0, h1, l1;
#pragma unroll
                for (int e = 0; e < 8; ++e) {
                    f16 hh = (f16)v0[e]; h0[e] = hh; l0[e] = (f16)(v0[e] - (float)hh);
                    f16 hh1 = (f16)v1[e]; h1[e] = hh1; l1[e] = (f16)(v1[e] - (float)hh1);
                }
                int Gb = cb >> 3;
                int off0 = o * 64 + ((Gb ^ (o & 7)) << 3);
                int off1 = o * 64 + (((Gb + 1) ^ (o & 7)) << 3);
                *(f16x8*)&Alh[off0] = h0; *(f16x8*)&All[off0] = l0;
                *(f16x8*)&Alh[off1] = h1; *(f16x8*)&All[off1] = l1;
            }
        }
        {
            int q4b = t & 31;
            int oc = t >> 5;
            const float* fp = featb + (size_t)(c0 + oc * 8) * DD + q4b * 4;
            float4 rr[8];
#pragma unroll
            for (int r = 0; r < 8; ++r) rr[r] = *(const float4*)(fp + (size_t)r * DD);
#pragma unroll
            for (int p = 0; p < 4; ++p) {
                int d = q4b * 4 + p;
                f16x8 hv, lv;
#pragma unroll
                for (int r = 0; r < 8; ++r) {
                    float x = (&rr[r].x)[p];
                    f16 hh = (f16)x;
                    hv[r] = hh; lv[r] = (f16)(x - (float)hh);
                }
                int off = d * 64 + ((oc ^ (d & 7)) << 3);
                *(f16x8*)&Blh[off] = hv;
                *(f16x8*)&Bll[off] = lv;
            }
        }
        __syncthreads();
#pragma unroll
        for (int s = 0; s < 2; ++s) {
            int G = s * 4 + g;
            f16x8 bfh[4], bfl[4];
#pragma unroll
            for (int nf = 0; nf < 4; ++nf) {
                int drow = wn * 64 + nf * 16 + col;
                int off = drow * 64 + ((G ^ (drow & 7)) << 3);
                bfh[nf] = *(const f16x8*)&Blh[off];
                bfl[nf] = *(const f16x8*)&Bll[off];
            }
#pragma unroll
            for (int mf = 0; mf < 4; ++mf) {
                int orow = wm * 64 + mf * 16 + col;
                int off = orow * 64 + ((G ^ (orow & 7)) << 3);
                f16x8 afh = *(const f16x8*)&Alh[off];
                f16x8 afl = *(const f16x8*)&All[off];
#pragma unroll
                for (int nf = 0; nf < 4; ++nf) {
                    acc[mf][nf] = __builtin_amdgcn_mfma_f32_16x16x32_f16(afh, bfh[nf], acc[mf][nf], 0, 0, 0);
                    acc[mf][nf] = __builtin_amdgcn_mfma_f32_16x16x32_f16(afl, bfh[nf], acc[mf][nf], 0, 0, 0);
                    acc[mf][nf] = __builtin_amdgcn_mfma_f32_16x16x32_f16(afh, bfl[nf], acc[mf][nf], 0, 0, 0);
                }
            }
        }
        __syncthreads();
    }

    f16* vb = vh + ((size_t)b * CC + o0) * DD + d0;
#pragma unroll
    for (int mf = 0; mf < 4; ++mf)
#pragma unroll
        for (int nf = 0; nf < 4; ++nf) {
#pragma unroll
            for (int r = 0; r < 4; ++r) {
                int o = wm * 64 + mf * 16 + g * 4 + r;
                int d = wn * 64 + nf * 16 + col;
                vb[(size_t)o * DD + d] = (f16)(acc[mf][nf][r] + bv[o0 + o]);
            }
        }
}

// softmax over 9 bins; sum the 128 per-slot partials (coalesced [slot][k][bc])
__global__ void sm_k(const float* __restrict__ dotp, float* __restrict__ A) {
    int i = blockIdx.x * 256 + threadIdx.x;
    if (i >= BB * CC) return;
    float s[9];
#pragma unroll
    for (int k = 0; k < 9; ++k) s[k] = 0.f;
    for (int p = 0; p < 128; ++p) {
        const float* dp = dotp + (size_t)p * (9 * BB * CC);
#pragma unroll
        for (int k = 0; k < 9; ++k) s[k] += dp[k * (BB * CC) + i];
    }
    float m = -1e30f;
    const float sc = 1.f / 64.f;
#pragma unroll
    for (int k = 0; k < 9; ++k) { s[k] *= sc; m = fmaxf(m, s[k]); }
    float sum = 0.f;
#pragma unroll
    for (int k = 0; k < 9; ++k) { s[k] = __expf(s[k] - m); sum += s[k]; }
    float inv = 1.f / sum;
#pragma unroll
    for (int k = 0; k < 9; ++k) A[(size_t)i * 9 + k] = s[k] * inv;
}

// out: each thread computes 4 consecutive w via float4.
__global__ __launch_bounds__(256) void out_k(const float* __restrict__ src,
                                             const f16* __restrict__ vh,
                                             const float* __restrict__ A,
                                             float* __restrict__ out) {
    __shared__ float Al[9];
    int bid = blockIdx.x;
    int bc = bid >> 4;
    int h0 = (bid & 15) << 3;
    int t = threadIdx.x;
    if (t < 9) Al[t] = A[(size_t)bc * 9 + t];
    __syncthreads();
    int h = h0 + (t >> 5);
    int a = t & 31;              // w = 4a..4a+3
    bool hodd = (h & 1) != 0;
    int iA = hodd ? 2 : 1;
    int yA = hodd ? ((h - 1) >> 1) : (h >> 1);
    int yB = (h + 1) >> 1;
    bool hasB = hodd && (yB < 64);

    const f16* vb = vh + (size_t)bc * DD;
    float s0 = 0.f, s1 = 0.f, s2 = 0.f, s3 = 0.f;
    {
        const f16* vr = vb + yA * OWW + 2 * a;
        f16x2 v01 = *(const f16x2*)vr;
        float V0 = (float)v01[0], V1 = (float)v01[1];
        float V2 = (2 * a + 2 < 64) ? (float)vr[2] : 0.f;
        float A0 = Al[iA * 3 + 0], A1 = Al[iA * 3 + 1], A2 = Al[iA * 3 + 2];
        s0 += A1 * V0;
        s1 += A0 * V1 + A2 * V0;
        s2 += A1 * V1;
        s3 += A0 * V2 + A2 * V1;
    }
    if (hasB) {
        const f16* vr = vb + yB * OWW + 2 * a;
        f16x2 v01 = *(const f16x2*)vr;
        float V0 = (float)v01[0], V1 = (float)v01[1];
        float V2 = (2 * a + 2 < 64) ? (float)vr[2] : 0.f;
        float A0 = Al[0], A1 = Al[1], A2 = Al[2];
        s0 += A1 * V0;
        s1 += A0 * V1 + A2 * V0;
        s2 += A1 * V1;
        s3 += A0 * V2 + A2 * V1;
    }
    size_t idx = (size_t)bc * NPIX + (size_t)h * WW + a * 4;
    float4 sv = *(const float4*)(src + idx);
    float4 o4;
    o4.x = s0 * sv.x; o4.y = s1 * sv.y; o4.z = s2 * sv.z; o4.w = s3 * sv.w;
    *(float4*)(out + idx) = o4;
}

extern "C" void kernel_launch(void* const* d_in, const int* in_sizes, int n_in,
                              void* d_out, int out_size, void* d_ws, size_t ws_size,
                              hipStream_t stream) {
    const float* feat = (const float*)d_in[0];
    const float* src  = (const float*)d_in[1];
    const float* Wq   = (const float*)d_in[2];
    const float* bq   = (const float*)d_in[3];
    const float* Wv   = (const float*)d_in[4];
    const float* bv   = (const float*)d_in[5];
    float* out = (float*)d_out;

    f16*  vh   = (f16*)d_ws;                                 // 8.39MB
    float* dotp = (float*)(vh + (size_t)BB * CC * DD);       // 128*9*1024*4 = 4.72MB
    float* A    = dotp + (size_t)128 * 9 * BB * CC;          // 36.9KB
    f16*  wqh  = (f16*)(A + (size_t)BB * CC * 9);            // 131KB
    f16*  wql  = wqh + 65536;                                // 131KB

    prep_wq_k<<<8, 256, 0, stream>>>(Wq, wqh, wql);
    qcdot_k<<<BB * 128, 512, 0, stream>>>(src, feat, wqh, wql, bq, dotp);
    vc_k<<<BB * 64, 256, 0, stream>>>(feat, Wv, bv, vh);
    sm_k<<<(BB * CC + 255) / 256, 256, 0, stream>>>(dotp, A);
    out_k<<<BB * CC * 16, 256, 0, stream>>>(src, vh, A, out);
}

// Round 8
// 128.501 us; speedup vs baseline: 1.0868x; 1.0868x over previous
//
#include <hip/hip_runtime.h>

typedef _Float16 f16;
typedef _Float16 f16x2 __attribute__((ext_vector_type(2)));
typedef _Float16 f16x4 __attribute__((ext_vector_type(4)));
typedef _Float16 f16x8 __attribute__((ext_vector_type(8)));
typedef float f32x4 __attribute__((ext_vector_type(4)));

#define BB 4
#define CC 256
#define HH 128
#define WW 128
#define OWW 64
#define DD 4096     // 64*64
#define NPIX 16384  // 128*128

// W -> hi/lo f16 per-lane MFMA fragment images:
// d{h,l}[((kk*8+G)*256 + o)*8 + e] = split(W[o][kk*64 + G*8 + e])
// blocks 0..7: Wq; blocks 8..15: Wv.
__global__ void prep_w_k(const float* __restrict__ Wq, const float* __restrict__ Wv,
                         f16* __restrict__ wqh, f16* __restrict__ wql,
                         f16* __restrict__ wvh, f16* __restrict__ wvl) {
    int bb = blockIdx.x;
    const float* W = (bb < 8) ? Wq : Wv;
    f16* dh = (bb < 8) ? wqh : wvh;
    f16* dl = (bb < 8) ? wql : wvl;
    int t = (bb & 7) * 256 + threadIdx.x;   // 0..2047
    int G = t >> 8, o = t & 255;
#pragma unroll
    for (int kk = 0; kk < 4; ++kk) {
        const float* wr = W + (size_t)o * CC + kk * 64 + G * 8;
        float4 a = *(const float4*)wr;
        float4 b2 = *(const float4*)(wr + 4);
        float v[8] = {a.x, a.y, a.z, a.w, b2.x, b2.y, b2.z, b2.w};
        f16x8 hv, lv;
#pragma unroll
        for (int e = 0; e < 8; ++e) {
            f16 hh = (f16)v[e];
            hv[e] = hh;
            lv[e] = (f16)(v[e] - (float)hh);
        }
        size_t idx = (size_t)(((kk * 8 + G) * 256) + o) * 8;
        *(f16x8*)&dh[idx] = hv;
        *(f16x8*)&dl[idx] = lv;
    }
}

// Fused qc = (Wq_h+Wq_l)@src + bq (f16 split MFMA, qc never stored) + dot epilogue.
// Barrier-free main loop: src A-fragments loaded DIRECTLY from global (8 strided
// dwords/lane, f32->f16 in-register), Wq B-fragments from pre-swizzled images.
// LDS = feat tile only; single __syncthreads after staging.
// Block = (b, h-pair, w-half). 512 thr, 8 waves: rh = wv>>2, o0 = (wv&3)*64.
__global__ __launch_bounds__(512, 4) void qcdot_k(const float* __restrict__ src,
                                                  const float* __restrict__ feat,
                                                  const f16* __restrict__ wqh,
                                                  const f16* __restrict__ wql,
                                                  const float* __restrict__ bq,
                                                  float* __restrict__ dotp) {
    __shared__ __align__(16) f16 Fl[512 * 36];     // feat [(o*2+yi)][36]  36.9KB

    int t = threadIdx.x;
    int bid = blockIdx.x;
    int b = bid >> 7;
    int hp = (bid >> 1) & 63;
    int wh = bid & 1;
    int h = hp * 2;
    int w0 = wh * 64;
    int x0 = wh * 32;
    int ybase = hp;

    // ---- stage feat tile (from f32): Fl[(o*2+yi)*36 + xi] ----
    {
        const float* fb = feat + (size_t)b * CC * DD;
        int o = t >> 1, yi = t & 1;
        int y = ybase + yi;
        const float* frow = fb + (size_t)o * DD + y * 64 + x0;
        f16* dst = &Fl[(o * 2 + yi) * 36];
        if (y < 64) {
#pragma unroll
            for (int k2 = 0; k2 < 8; ++k2) {
                float4 f = *(const float4*)&frow[k2 * 4];
                f16x4 hv = {(f16)f.x, (f16)f.y, (f16)f.z, (f16)f.w};
                *(f16x4*)&dst[k2 * 4] = hv;
            }
            dst[32] = (x0 + 32 < 64) ? (f16)frow[32] : (f16)0.f;
        } else {
            f16x4 z = {0, 0, 0, 0};
#pragma unroll
            for (int k2 = 0; k2 < 8; ++k2) *(f16x4*)&dst[k2 * 4] = z;
            dst[32] = (f16)0.f;
        }
    }
    __syncthreads();

    int wv = t >> 6;
    int lane = t & 63;
    int g = lane >> 4;
    int col = lane & 15;
    int rh = wv >> 2;
    int o0 = (wv & 3) * 64;

    f32x4 acc[4][4];
#pragma unroll
    for (int mf = 0; mf < 4; ++mf)
#pragma unroll
        for (int nf = 0; nf < 4; ++nf) acc[mf][nf] = (f32x4){0.f, 0.f, 0.f, 0.f};

    // wave's src row base: row h+rh, w-range w0..w0+63
    const float* srcw = src + (size_t)b * CC * NPIX + (size_t)(h + rh) * WW + w0;

#pragma unroll
    for (int kk = 0; kk < 4; ++kk) {
#pragma unroll
        for (int s = 0; s < 2; ++s) {
            int G = s * 4 + g;
            int cb = kk * 64 + G * 8;
            // A-fragments: src[c][px] direct, f32 -> f16 in-register
            f16x8 af[4];
#pragma unroll
            for (int mf = 0; mf < 4; ++mf) {
                const float* sp = srcw + (size_t)cb * NPIX + mf * 16 + col;
                float x[8];
#pragma unroll
                for (int e = 0; e < 8; ++e) x[e] = sp[(size_t)e * NPIX];
                f16x8 hv = {(f16)x[0], (f16)x[1], (f16)x[2], (f16)x[3],
                            (f16)x[4], (f16)x[5], (f16)x[6], (f16)x[7]};
                af[mf] = hv;
            }
            // B-fragments hi, 16 MFMA
            f16x8 bf[4];
#pragma unroll
            for (int nf = 0; nf < 4; ++nf) {
                size_t idx = (size_t)(((kk * 8 + G) * 256) + o0 + nf * 16 + col) * 8;
                bf[nf] = *(const f16x8*)&wqh[idx];
            }
#pragma unroll
            for (int mf = 0; mf < 4; ++mf)
#pragma unroll
                for (int nf = 0; nf < 4; ++nf)
                    acc[mf][nf] = __builtin_amdgcn_mfma_f32_16x16x32_f16(af[mf], bf[nf], acc[mf][nf], 0, 0, 0);
            // B-fragments lo, 16 MFMA
#pragma unroll
            for (int nf = 0; nf < 4; ++nf) {
                size_t idx = (size_t)(((kk * 8 + G) * 256) + o0 + nf * 16 + col) * 8;
                bf[nf] = *(const f16x8*)&wql[idx];
            }
#pragma unroll
            for (int mf = 0; mf < 4; ++mf)
#pragma unroll
                for (int nf = 0; nf < 4; ++nf)
                    acc[mf][nf] = __builtin_amdgcn_mfma_f32_16x16x32_f16(af[mf], bf[nf], acc[mf][nf], 0, 0, 0);
        }
    }

    // ---- epilogue ----
    int i0 = rh ? 2 : 1;
    float bqv[4];
#pragma unroll
    for (int nf = 0; nf < 4; ++nf) bqv[nf] = bq[o0 + nf * 16 + col];

    float bins[4][2][3];
#pragma unroll
    for (int nf = 0; nf < 4; ++nf)
#pragma unroll
        for (int ii = 0; ii < 2; ++ii)
#pragma unroll
            for (int j = 0; j < 3; ++j) bins[nf][ii][j] = 0.f;

#pragma unroll
    for (int mf = 0; mf < 4; ++mf) {
        int X = mf * 8 + g * 2;
#pragma unroll
        for (int ii = 0; ii < 2; ++ii) {
            if (ii == 1 && rh == 0) continue;   // wave-uniform skip
#pragma unroll
            for (int nf = 0; nf < 4; ++nf) {
                int o = o0 + nf * 16 + col;
                const f16* fr = &Fl[(o * 2 + ii) * 36];
                f16x2 lh = *(const f16x2*)&fr[X];
                float lo = (float)lh[0], hi = (float)lh[1];
                float s2 = (float)fr[X + 2];
                float qv0 = acc[mf][nf][0] + bqv[nf];
                float qv1 = acc[mf][nf][1] + bqv[nf];
                float qv2 = acc[mf][nf][2] + bqv[nf];
                float qv3 = acc[mf][nf][3] + bqv[nf];
                bins[nf][ii][1] += qv0 * lo + qv2 * hi;   // j=1 (even w)
                bins[nf][ii][2] += qv1 * lo + qv3 * hi;   // j=2 (odd w, left)
                bins[nf][ii][0] += qv1 * hi + qv3 * s2;   // j=0 (odd w, right)
            }
        }
    }

#pragma unroll
    for (int m = 16; m <= 32; m <<= 1)
#pragma unroll
        for (int nf = 0; nf < 4; ++nf)
#pragma unroll
            for (int ii = 0; ii < 2; ++ii) {
                if (ii == 1 && rh == 0) continue;
#pragma unroll
                for (int j = 0; j < 3; ++j)
                    bins[nf][ii][j] += __shfl_xor(bins[nf][ii][j], m, 64);
            }

    if (g == 0) {
        float* dslot = dotp + (size_t)(bid & 127) * (9 * BB * CC);
#pragma unroll
        for (int nf = 0; nf < 4; ++nf) {
            int bc = b * CC + o0 + nf * 16 + col;
            dslot[(i0 * 3 + 0) * (BB * CC) + bc] = bins[nf][0][0];
            dslot[(i0 * 3 + 1) * (BB * CC) + bc] = bins[nf][0][1];
            dslot[(i0 * 3 + 2) * (BB * CC) + bc] = bins[nf][0][2];
            if (rh) {
                dslot[0 * (BB * CC) + bc] = bins[nf][1][0];
                dslot[1 * (BB * CC) + bc] = bins[nf][1][1];
                dslot[2 * (BB * CC) + bc] = bins[nf][1][2];
            }
        }
    }
}

// v = (Wv_h+Wv_l)@(feat_h+feat_l) + bv, split f16 MFMA (3 products) -> vh f16.
// Barrier-free, no LDS: Wv from frag images, feat direct-global with in-reg split.
// 512 thr, 8 waves (wm 2 x wn 4), wave tile 32o x 64d; block 64o x 256d.
// Grid = 4b x 4 o-tiles x 16 d-tiles = 256 blocks, 2048 waves.
__global__ __launch_bounds__(512, 4) void vc_k(const float* __restrict__ feat,
                                               const f16* __restrict__ wvh,
                                               const f16* __restrict__ wvl,
                                               const float* __restrict__ bv,
                                               f16* __restrict__ vh) {
    int t = threadIdx.x;
    int bid = blockIdx.x;
    int b = bid >> 6;
    int rest = bid & 63;
    int ot = rest >> 4;          // 0..3
    int dt = rest & 15;          // 0..15

    int wv = t >> 6;
    int wm = wv >> 2;            // 0..1
    int wn = wv & 3;             // 0..3
    int lane = t & 63;
    int g = lane >> 4;
    int col = lane & 15;

    int o_w = ot * 64 + wm * 32;
    int d_w = dt * 256 + wn * 64;

    f32x4 acc[2][4];
#pragma unroll
    for (int mf = 0; mf < 2; ++mf)
#pragma unroll
        for (int nf = 0; nf < 4; ++nf) acc[mf][nf] = (f32x4){0.f, 0.f, 0.f, 0.f};

    const float* fb = feat + (size_t)b * CC * DD;

#pragma unroll
    for (int kk = 0; kk < 4; ++kk) {
#pragma unroll
        for (int s = 0; s < 2; ++s) {
            int G = s * 4 + g;
            int cb = kk * 64 + G * 8;
            // B-fragments: feat[c][d] direct, split hi/lo in-register
            f16x8 bfh[4], bfl[4];
#pragma unroll
            for (int nf = 0; nf < 4; ++nf) {
                const float* fp = fb + (size_t)cb * DD + d_w + nf * 16 + col;
                float x[8];
#pragma unroll
                for (int e = 0; e < 8; ++e) x[e] = fp[(size_t)e * DD];
                f16x8 hv, lv;
#pragma unroll
                for (int e = 0; e < 8; ++e) {
                    f16 hh = (f16)x[e];
                    hv[e] = hh;
                    lv[e] = (f16)(x[e] - (float)hh);
                }
                bfh[nf] = hv;
                bfl[nf] = lv;
            }
            // A-fragments (Wv hi/lo) from images
            f16x8 afh[2], afl[2];
#pragma unroll
            for (int mf = 0; mf < 2; ++mf) {
                size_t idx = (size_t)(((kk * 8 + G) * 256) + o_w + mf * 16 + col) * 8;
                afh[mf] = *(const f16x8*)&wvh[idx];
                afl[mf] = *(const f16x8*)&wvl[idx];
            }
            // 3 products: Wh*Fh + Wl*Fh + Wh*Fl
#pragma unroll
            for (int mf = 0; mf < 2; ++mf)
#pragma unroll
                for (int nf = 0; nf < 4; ++nf)
                    acc[mf][nf] = __builtin_amdgcn_mfma_f32_16x16x32_f16(afh[mf], bfh[nf], acc[mf][nf], 0, 0, 0);
#pragma unroll
            for (int mf = 0; mf < 2; ++mf)
#pragma unroll
                for (int nf = 0; nf < 4; ++nf)
                    acc[mf][nf] = __builtin_amdgcn_mfma_f32_16x16x32_f16(afl[mf], bfh[nf], acc[mf][nf], 0, 0, 0);
#pragma unroll
            for (int mf = 0; mf < 2; ++mf)
#pragma unroll
                for (int nf = 0; nf < 4; ++nf)
                    acc[mf][nf] = __builtin_amdgcn_mfma_f32_16x16x32_f16(afh[mf], bfl[nf], acc[mf][nf], 0, 0, 0);
        }
    }

    f16* vb = vh + (size_t)b * CC * DD;
#pragma unroll
    for (int mf = 0; mf < 2; ++mf)
#pragma unroll
        for (int nf = 0; nf < 4; ++nf) {
#pragma unroll
            for (int r = 0; r < 4; ++r) {
                int o = o_w + mf * 16 + g * 4 + r;
                int d = d_w + nf * 16 + col;
                vb[(size_t)o * DD + d] = (f16)(acc[mf][nf][r] + bv[o]);
            }
        }
}

// softmax over 9 bins; sum the 128 per-slot partials (coalesced [slot][k][bc])
__global__ void sm_k(const float* __restrict__ dotp, float* __restrict__ A) {
    int i = blockIdx.x * 256 + threadIdx.x;
    if (i >= BB * CC) return;
    float s[9];
#pragma unroll
    for (int k = 0; k < 9; ++k) s[k] = 0.f;
    for (int p = 0; p < 128; ++p) {
        const float* dp = dotp + (size_t)p * (9 * BB * CC);
#pragma unroll
        for (int k = 0; k < 9; ++k) s[k] += dp[k * (BB * CC) + i];
    }
    float m = -1e30f;
    const float sc = 1.f / 64.f;
#pragma unroll
    for (int k = 0; k < 9; ++k) { s[k] *= sc; m = fmaxf(m, s[k]); }
    float sum = 0.f;
#pragma unroll
    for (int k = 0; k < 9; ++k) { s[k] = __expf(s[k] - m); sum += s[k]; }
    float inv = 1.f / sum;
#pragma unroll
    for (int k = 0; k < 9; ++k) A[(size_t)i * 9 + k] = s[k] * inv;
}

// out: each thread computes 4 consecutive w via float4.
__global__ __launch_bounds__(256) void out_k(const float* __restrict__ src,
                                             const f16* __restrict__ vh,
                                             const float* __restrict__ A,
                                             float* __restrict__ out) {
    __shared__ float Al[9];
    int bid = blockIdx.x;
    int bc = bid >> 4;
    int h0 = (bid & 15) << 3;
    int t = threadIdx.x;
    if (t < 9) Al[t] = A[(size_t)bc * 9 + t];
    __syncthreads();
    int h = h0 + (t >> 5);
    int a = t & 31;              // w = 4a..4a+3
    bool hodd = (h & 1) != 0;
    int iA = hodd ? 2 : 1;
    int yA = hodd ? ((h - 1) >> 1) : (h >> 1);
    int yB = (h + 1) >> 1;
    bool hasB = hodd && (yB < 64);

    const f16* vb = vh + (size_t)bc * DD;
    float s0 = 0.f, s1 = 0.f, s2 = 0.f, s3 = 0.f;
    {
        const f16* vr = vb + yA * OWW + 2 * a;
        f16x2 v01 = *(const f16x2*)vr;
        float V0 = (float)v01[0], V1 = (float)v01[1];
        float V2 = (2 * a + 2 < 64) ? (float)vr[2] : 0.f;
        float A0 = Al[iA * 3 + 0], A1 = Al[iA * 3 + 1], A2 = Al[iA * 3 + 2];
        s0 += A1 * V0;
        s1 += A0 * V1 + A2 * V0;
        s2 += A1 * V1;
        s3 += A0 * V2 + A2 * V1;
    }
    if (hasB) {
        const f16* vr = vb + yB * OWW + 2 * a;
        f16x2 v01 = *(const f16x2*)vr;
        float V0 = (float)v01[0], V1 = (float)v01[1];
        float V2 = (2 * a + 2 < 64) ? (float)vr[2] : 0.f;
        float A0 = Al[0], A1 = Al[1], A2 = Al[2];
        s0 += A1 * V0;
        s1 += A0 * V1 + A2 * V0;
        s2 += A1 * V1;
        s3 += A0 * V2 + A2 * V1;
    }
    size_t idx = (size_t)bc * NPIX + (size_t)h * WW + a * 4;
    float4 sv = *(const float4*)(src + idx);
    float4 o4;
    o4.x = s0 * sv.x; o4.y = s1 * sv.y; o4.z = s2 * sv.z; o4.w = s3 * sv.w;
    *(float4*)(out + idx) = o4;
}

extern "C" void kernel_launch(void* const* d_in, const int* in_sizes, int n_in,
                              void* d_out, int out_size, void* d_ws, size_t ws_size,
                              hipStream_t stream) {
    const float* feat = (const float*)d_in[0];
    const float* src  = (const float*)d_in[1];
    const float* Wq   = (const float*)d_in[2];
    const float* bq   = (const float*)d_in[3];
    const float* Wv   = (const float*)d_in[4];
    const float* bv   = (const float*)d_in[5];
    float* out = (float*)d_out;

    f16*  vh   = (f16*)d_ws;                                 // 8.39MB
    float* dotp = (float*)(vh + (size_t)BB * CC * DD);       // 4.72MB
    float* A    = dotp + (size_t)128 * 9 * BB * CC;          // 36.9KB
    f16*  wqh  = (f16*)(A + (size_t)BB * CC * 9);            // 131KB
    f16*  wql  = wqh + 65536;                                // 131KB
    f16*  wvh  = wql + 65536;                                // 131KB
    f16*  wvl  = wvh + 65536;                                // 131KB

    prep_w_k<<<16, 256, 0, stream>>>(Wq, Wv, wqh, wql, wvh, wvl);
    qcdot_k<<<BB * 128, 512, 0, stream>>>(src, feat, wqh, wql, bq, dotp);
    vc_k<<<256, 512, 0, stream>>>(feat, wvh, wvl, bv, vh);
    sm_k<<<(BB * CC + 255) / 256, 256, 0, stream>>>(dotp, A);
    out_k<<<BB * CC * 16, 256, 0, stream>>>(src, vh, A, out);
}